// Round 1
// baseline (355.172 us; speedup 1.0000x reference)
//
#include <hip/hip_runtime.h>
#include <math.h>

// SparseMOELayer: N=65536 tokens, D=128, E=16 experts, top-3 routing.
// Outputs concat: logits[N*D] | importance_loss[1] | comb[N*E]
//
// R1 (this round): occupancy fix. yacc store-staging buffer halved
// (64x132 f32 -> 32x132 f32, two-pass store) so LDS drops 52.7K -> 35.9K
// => 4 blocks/CU (grid 1024 = fully resident on 256 CUs, no tail).
// __launch_bounds__(256,4) pins 4 waves/SIMD (VGPR 124 <= 128 already).
// Also vectorized x->bf16 restage (float4->bf16x4) and final store (float4).
#define NTOK 65536
#define DD   128
#define NE   16
#define NK   3
#define TPB  64                    // tokens per block
#define NBLK (NTOK / TPB)          // 1024

#define OUT_LOSS ((size_t)NTOK * DD)
#define OUT_COMB ((size_t)NTOK * DD + 1)

typedef __bf16 bf16x8 __attribute__((ext_vector_type(8)));
typedef __bf16 bf16x4 __attribute__((ext_vector_type(4)));
typedef float  f32x4  __attribute__((ext_vector_type(4)));

__device__ __forceinline__ double softplus_d(double z) {
    return fmax(z, 0.0) + log1p(exp(-fabs(z)));
}

// ---------------------------------------------------------------------------
// K0: pack We[e][d][f] fp32 -> WeTp bf16, FRAGMENT-MAJOR:
//   WeTp[e][nt][s][lane][j]  (flat: e*16384 + (nt*4+s)*512 + lane*8 + j)
//   holds We[d = s*32 + (lane>>4)*8 + j][f = nt*16 + (lane&15)].
// Consumer loadBp then reads one bf16x8/lane at consecutive 16B -> each
// B-frag load is ONE coalesced 1KB transaction.
// 64 blocks: (expert e = blk>>2, k-step s = blk&3). Block 0 zeroes imp_g.
// ---------------------------------------------------------------------------
__global__ __launch_bounds__(256) void k_prep(
    const float* __restrict__ We, __bf16* __restrict__ WeTp,
    float* __restrict__ imp_g)
{
    __shared__ __bf16 S[32][DD + 8];
    const int tid = threadIdx.x;
    const int e  = blockIdx.x >> 2;
    const int qd = blockIdx.x & 3;             // == k-step s
    if (blockIdx.x == 0 && tid < NE) imp_g[tid] = 0.f;
    const size_t base = (size_t)e * DD * DD + (size_t)qd * 32 * DD;
    for (int i = tid; i < 32 * DD; i += 256) { // coalesced read, d-quarter
        int dd = i >> 7, f = i & 127;
        S[dd][f] = (__bf16)We[base + i];
    }
    __syncthreads();
    #pragma unroll
    for (int it = 0; it < 2; it++) {
        int lin  = it * 256 + tid;             // 0..511 vectors
        int nt   = lin >> 6;
        int lane = lin & 63;
        int quad = lane >> 4, l15 = lane & 15;
        int f = nt * 16 + l15;
        bf16x8 vv;
        #pragma unroll
        for (int j = 0; j < 8; j++) vv[j] = S[quad * 8 + j][f];
        *(bf16x8*)(WeTp + (size_t)e * 16384 +
                   ((size_t)(nt * 4 + qd) * 64 + lane) * 8) = vv;   // coalesced
    }
}

// ---------------------------------------------------------------------------
// Load one expert's B fragments (2 n-tiles x 4 k-steps) from packed WeTp.
// Each load: lane-consecutive 16B -> one 1KB coalesced transaction.
// ---------------------------------------------------------------------------
__device__ __forceinline__ void loadBp(
    bf16x8 (&dst)[2][4], const __bf16* __restrict__ WeTp,
    int e, int wid, int lane)
{
    const __bf16* b = WeTp + (size_t)e * 16384 + (size_t)lane * 8;
    #pragma unroll
    for (int t2 = 0; t2 < 2; t2++)
        #pragma unroll
        for (int s = 0; s < 4; s++)
            dst[t2][s] = *(const bf16x8*)(b + ((wid * 2 + t2) * 4 + s) * 512);
}

// ---------------------------------------------------------------------------
// K1: FUSED gate + expert. 64 tokens/block.
// Gate phases (fp64, R3-verified numerics) -> top-3 -> comb (LDS-direct +
// global write) -> dense MFMA expert loop (register-resident, packed
// coalesced B) -> bias epilogue -> coalesced store (two 32-row halves).
// Importance: LDS partials -> one global atomicAdd per expert per block
// (imp_g zeroed by k_prep, stream-ordered).
// LDS (35.9 KB total -> 4 blocks/CU, grid fully resident):
//   union u: gate fp64 scratch (17.4K) | xsb bf16 (17.4K) | yh f32 half (16.9K)
//   union v: WgT+WnT (16.9K, dead after dot phase) | beS+combT (12.5K)
// MFMA 16x16x32 layouts (m89-verified):
//   A: lane l holds A[m=l&15][k=(l>>4)*8+j]; D: col=l&15, row=(l>>4)*4+reg
// ---------------------------------------------------------------------------
__global__ __launch_bounds__(256, 4) void k_fused(
    const float* __restrict__ x, const float* __restrict__ noise,
    const float* __restrict__ Wg, const float* __restrict__ bg,
    const float* __restrict__ Wn, const float* __restrict__ bn,
    const __bf16* __restrict__ WeTp, const float* __restrict__ be,
    float* __restrict__ out, float* __restrict__ imp_g)
{
    __shared__ union {
        struct { double ga[TPB][NE + 1]; double na[TPB][NE + 1]; } g;  // 17.4K
        __bf16 xsb[TPB][DD + 8];                                       // 17.4K
        float  yh[32][DD + 4];                                         // 16.9K
    } u;
    __shared__ union {
        struct { float WgT[NE][DD + 4]; float WnT[NE][DD + 4]; } w;    // 16.9K
        struct { float beS[NE][DD]; float combT[NE][TPB + 4]; } p;     // 12.5K
    } v;
    __shared__ float tkw[TPB][NK];
    __shared__ int   tke[TPB][NK];
    __shared__ float impS[NE];

    const int tid  = threadIdx.x;
    const int n0   = blockIdx.x * TPB;
    const int lane = tid & 63;
    const int wid  = tid >> 6;             // wave -> cols wid*32..+31
    const int l15  = lane & 15;
    const int quad = lane >> 4;
    const int e16  = tid & 15;             // gate-phase expert id
    const int tl   = tid >> 4;             // gate-phase token lane

    // ---- G1: stage transposed gate weights; zero impS ----
    if (tid < NE) impS[tid] = 0.0f;
    for (int i = tid; i < DD * NE; i += 256) {
        int d = i >> 4, ee = i & 15;
        v.w.WgT[ee][d] = Wg[i];
        v.w.WnT[ee][d] = Wn[i];
    }
    __syncthreads();

    // ---- G2: fp64 dots (8 indep chains); x via 16-lane broadcast float4 ----
    {
        const float4* wgp = (const float4*)&v.w.WgT[e16][0];
        const float4* wnp = (const float4*)&v.w.WnT[e16][0];
        for (int g = 0; g < 4; g++) {
            int t = g * 16 + tl;
            const float4* xp = (const float4*)(x + (size_t)(n0 + t) * DD);
            double g0 = 0, g1 = 0, g2 = 0, g3 = 0;
            double h0 = 0, h1 = 0, h2 = 0, h3 = 0;
            #pragma unroll 4
            for (int q = 0; q < DD / 4; q++) {
                float4 xv = xp[q], wg = wgp[q], wn = wnp[q];
                g0 += (double)xv.x * wg.x; g1 += (double)xv.y * wg.y;
                g2 += (double)xv.z * wg.z; g3 += (double)xv.w * wg.w;
                h0 += (double)xv.x * wn.x; h1 += (double)xv.y * wn.y;
                h2 += (double)xv.z * wn.z; h3 += (double)xv.w * wn.w;
            }
            u.g.ga[t][e16] = (g0 + g1) + (g2 + g3);
            u.g.na[t][e16] = (h0 + h1) + (h2 + h3);
        }
    }
    __syncthreads();

    // ---- G3: gate = ga + bg + noise * softplus(na + bn) ----
    {
        const double bge = (double)bg[e16], bne = (double)bn[e16];
        for (int g = 0; g < 4; g++) {
            int t = g * 16 + tl;
            double nz = (double)noise[(size_t)(n0 + t) * NE + e16];
            u.g.ga[t][e16] = u.g.ga[t][e16] + bge
                           + nz * softplus_d(u.g.na[t][e16] + bne);
        }
    }
    __syncthreads();

    // ---- G4: top-3 + softmax (64 threads) ----
    if (tid < TPB) {
        int t = tid;
        double vk[NK]; int ix[NK];
        unsigned taken = 0;
        for (int k = 0; k < NK; k++) {
            double best = -INFINITY; int bi = 0;
            for (int j = 0; j < NE; j++) {
                if (!((taken >> j) & 1u)) {
                    double gv = u.g.ga[t][j];
                    if (gv > best) { best = gv; bi = j; }  // strict >: low idx tie
                }
            }
            taken |= 1u << bi;
            vk[k] = best; ix[k] = bi;
        }
        double e1 = exp(vk[1] - vk[0]);
        double e2 = exp(vk[2] - vk[0]);
        double inv = 1.0 / (1.0 + e1 + e2);
        tke[t][0] = ix[0]; tke[t][1] = ix[1]; tke[t][2] = ix[2];
        tkw[t][0] = (float)inv;
        tkw[t][1] = (float)(e1 * inv);
        tkw[t][2] = (float)(e2 * inv);
    }
    __syncthreads();   // gate scratch (u.g) dead; v.w dead -> stage new data

    // ---- G5/X1: comb (global + LDS combT), impS, beS, xsb staging ----
    for (int g = 0; g < 4; g++) {
        int t = g * 16 + tl;
        float c = 0.f;
        if (tke[t][0] == e16) c = tkw[t][0];
        if (tke[t][1] == e16) c = tkw[t][1];
        if (tke[t][2] == e16) c = tkw[t][2];
        out[OUT_COMB + (size_t)(n0 + t) * NE + e16] = c;
        v.p.combT[e16][t] = c;
        if (c != 0.f) atomicAdd(&impS[e16], c);
    }
    for (int idx = tid; idx < NE * DD; idx += 256)      // stage be
        v.p.beS[idx >> 7][idx & 127] = be[idx];
    for (int idx = tid; idx < TPB * DD / 4; idx += 256) {   // stage x as bf16 (vec)
        int t = idx >> 5, q = idx & 31;
        float4 xv = *(const float4*)(x + (size_t)(n0 + t) * DD + q * 4);
        bf16x4 bv = { (__bf16)xv.x, (__bf16)xv.y, (__bf16)xv.z, (__bf16)xv.w };
        *(bf16x4*)&u.xsb[t][q * 4] = bv;
    }
    __syncthreads();

    // importance partials -> global (device-scope atomics)
    if (tid < NE) atomicAdd(&imp_g[tid], impS[tid]);

    // ---- X2: hoist A fragments (expert-independent, read LDS once) ----
    bf16x8 Af[4][4];
    #pragma unroll
    for (int a = 0; a < 4; a++)
        #pragma unroll
        for (int s = 0; s < 4; s++)
            Af[a][s] = *(const bf16x8*)&u.xsb[a * 16 + l15][32 * s + quad * 8];
    __syncthreads();   // xsb dead -> u.yh reusable

    // ---- X3: expert loop, register-resident, dbuf coalesced B ----
    f32x4 logits[4][2];
    #pragma unroll
    for (int a = 0; a < 4; a++) {
        logits[a][0] = (f32x4){0.f, 0.f, 0.f, 0.f};
        logits[a][1] = (f32x4){0.f, 0.f, 0.f, 0.f};
    }
    bf16x8 Bf[2][2][4];
    loadBp(Bf[0], WeTp, 0, wid, lane);

    #pragma unroll 2
    for (int e = 0; e < NE; e++) {
        const int cur = e & 1;
        if (e + 1 < NE) loadBp(Bf[cur ^ 1], WeTp, e + 1, wid, lane);

        f32x4 acc[4][2];
        #pragma unroll
        for (int a = 0; a < 4; a++) {
            acc[a][0] = (f32x4){0.f, 0.f, 0.f, 0.f};
            acc[a][1] = (f32x4){0.f, 0.f, 0.f, 0.f};
        }
        #pragma unroll
        for (int s = 0; s < 4; s++)        // s-outer: 8 indep chains
            #pragma unroll
            for (int a = 0; a < 4; a++) {
                acc[a][0] = __builtin_amdgcn_mfma_f32_16x16x32_bf16(
                    Af[a][s], Bf[cur][0][s], acc[a][0], 0, 0, 0);
                acc[a][1] = __builtin_amdgcn_mfma_f32_16x16x32_bf16(
                    Af[a][s], Bf[cur][1][s], acc[a][1], 0, 0, 0);
            }
        #pragma unroll
        for (int a = 0; a < 4; a++) {
            f32x4 cv = *(const f32x4*)&v.p.combT[e][a * 16 + quad * 4];
            #pragma unroll
            for (int r = 0; r < 4; r++) {
                logits[a][0][r] = fmaf(cv[r], acc[a][0][r], logits[a][0][r]);
                logits[a][1][r] = fmaf(cv[r], acc[a][1][r], logits[a][1][r]);
            }
        }
    }

    // ---- X4: bias epilogue + LDS-staged coalesced store (two halves) ----
    const int nA = wid * 32, nB = nA + 16;
    #pragma unroll 4
    for (int e = 0; e < NE; e++) {
        float bA = v.p.beS[e][nA + l15];
        float bB = v.p.beS[e][nB + l15];
        #pragma unroll
        for (int a = 0; a < 4; a++) {
            f32x4 cv = *(const f32x4*)&v.p.combT[e][a * 16 + quad * 4];
            #pragma unroll
            for (int r = 0; r < 4; r++) {
                logits[a][0][r] = fmaf(cv[r], bA, logits[a][0][r]);
                logits[a][1][r] = fmaf(cv[r], bB, logits[a][1][r]);
            }
        }
    }
    #pragma unroll
    for (int h = 0; h < 2; h++) {
        __syncthreads();                    // h=0: after X2 reads; h=1: after copy
        #pragma unroll
        for (int a2 = 0; a2 < 2; a2++) {
            const int a = h * 2 + a2;
            #pragma unroll
            for (int r = 0; r < 4; r++) {
                int row = a2 * 16 + quad * 4 + r;   // 0..31 within half
                u.yh[row][nA + l15] = logits[a][0][r];
                u.yh[row][nB + l15] = logits[a][1][r];
            }
        }
        __syncthreads();
        float4* op4 = (float4*)(out + ((size_t)n0 + h * 32) * DD);
        for (int idx = tid; idx < 32 * DD / 4; idx += 256) {
            int t = idx >> 5, q = idx & 31;
            op4[idx] = *(const float4*)&u.yh[t][q * 4];
        }
    }
}

// ---------------------------------------------------------------------------
// K2: loss from 16 globally-accumulated importances (atomic sums from k_fused).
// ---------------------------------------------------------------------------
__global__ __launch_bounds__(64) void k_loss(
    const float* __restrict__ imp_g, float* __restrict__ out)
{
    if (threadIdx.x == 0) {
        double mean = 0.0;
        for (int i = 0; i < NE; i++) mean += (double)imp_g[i];
        mean /= NE;
        double var = 0.0;
        for (int i = 0; i < NE; i++) {
            double d = (double)imp_g[i] - mean; var += d * d;
        }
        var /= (NE - 1);                    // ddof=1
        out[OUT_LOSS] = (float)(var / (mean * mean));
    }
}

// ---------------------------------------------------------------------------
extern "C" void kernel_launch(void* const* d_in, const int* in_sizes, int n_in,
                              void* d_out, int out_size, void* d_ws, size_t ws_size,
                              hipStream_t stream)
{
    (void)in_sizes; (void)n_in; (void)out_size; (void)ws_size;
    const float* x     = (const float*)d_in[0];
    const float* noise = (const float*)d_in[1];
    const float* Wg    = (const float*)d_in[2];
    const float* bg    = (const float*)d_in[3];
    const float* Wn    = (const float*)d_in[4];
    const float* bn    = (const float*)d_in[5];
    const float* We    = (const float*)d_in[6];
    const float* be    = (const float*)d_in[7];
    float* out = (float*)d_out;

    char*   ws    = (char*)d_ws;
    float*  imp_g = (float*)ws;                  // 64 B (16 floats)
    __bf16* WeTp  = (__bf16*)(ws + 1024);        // 512 KB, 16B-aligned

    hipLaunchKernelGGL(k_prep, dim3(64), dim3(256), 0, stream,
                       We, WeTp, imp_g);
    hipLaunchKernelGGL(k_fused, dim3(NBLK), dim3(256), 0, stream,
                       x, noise, Wg, bg, Wn, bn, WeTp, be, out, imp_g);
    hipLaunchKernelGGL(k_loss, dim3(1), dim3(64), 0, stream, imp_g, out);
}

// Round 3
// 202.457 us; speedup vs baseline: 1.7543x; 1.7543x over previous
//
#include <hip/hip_runtime.h>
#include <math.h>

// SparseMOELayer: N=65536 tokens, D=128, E=16 experts, top-3 routing.
// Outputs concat: logits[N*D] | importance_loss[1] | comb[N*E]
//
// R3: revert f64-MFMA gate (R2 layout unverified -> wrong top-k). Base = R0
// proven structure. Deltas, all numerics-identical:
//  (a) Wg/Wn staged to LDS as fp64 -> gate inner loop loses 8 of 12
//      v_cvt_f64_f32 per q-iter (gate VALU -40%); sums bit-identical.
//  (b) G3 fused into G2 (gate in-register, na[] LDS + 1 barrier removed).
//  (c) k_loss merged into k_fused via ticket counter (-1 launch).
//  (d) R1's halved yh store-staging + vectorized bf16 restage (proven).
//  (e) expert-0 B-fragments issued at kernel entry (L2 latency under gate).
// launch_bounds stays (256,2): R1 proved unified VGPR+AGPR need ~190.
#define NTOK 65536
#define DD   128
#define NE   16
#define NK   3
#define TPB  64                    // tokens per block
#define NBLK (NTOK / TPB)          // 1024

#define OUT_LOSS ((size_t)NTOK * DD)
#define OUT_COMB ((size_t)NTOK * DD + 1)

typedef __bf16 bf16x8 __attribute__((ext_vector_type(8)));
typedef __bf16 bf16x4 __attribute__((ext_vector_type(4)));
typedef float  f32x4  __attribute__((ext_vector_type(4)));

__device__ __forceinline__ double softplus_d(double z) {
    return fmax(z, 0.0) + log1p(exp(-fabs(z)));
}

// ---------------------------------------------------------------------------
// K0: pack We[e][d][f] fp32 -> WeTp bf16, FRAGMENT-MAJOR:
//   WeTp[e][nt][s][lane][j]  (flat: e*16384 + (nt*4+s)*512 + lane*8 + j)
//   holds We[d = s*32 + (lane>>4)*8 + j][f = nt*16 + (lane&15)].
// Consumer loadBp then reads one bf16x8/lane at consecutive 16B -> each
// B-frag load is ONE coalesced 1KB transaction.
// 64 blocks: (expert e = blk>>2, k-step s = blk&3). Block 0 zeroes imp_g
// and the loss ticket.
// ---------------------------------------------------------------------------
__global__ __launch_bounds__(256) void k_prep(
    const float* __restrict__ We, __bf16* __restrict__ WeTp,
    float* __restrict__ imp_g, unsigned* __restrict__ ticket)
{
    __shared__ __bf16 S[32][DD + 8];
    const int tid = threadIdx.x;
    const int e  = blockIdx.x >> 2;
    const int qd = blockIdx.x & 3;             // == k-step s
    if (blockIdx.x == 0) {
        if (tid < NE) imp_g[tid] = 0.f;
        if (tid == NE) *ticket = 0u;
    }
    const size_t base = (size_t)e * DD * DD + (size_t)qd * 32 * DD;
    for (int i = tid; i < 32 * DD; i += 256) { // coalesced read, d-quarter
        int dd = i >> 7, f = i & 127;
        S[dd][f] = (__bf16)We[base + i];
    }
    __syncthreads();
    #pragma unroll
    for (int it = 0; it < 2; it++) {
        int lin  = it * 256 + tid;             // 0..511 vectors
        int nt   = lin >> 6;
        int lane = lin & 63;
        int quad = lane >> 4, l15 = lane & 15;
        int f = nt * 16 + l15;
        bf16x8 vv;
        #pragma unroll
        for (int j = 0; j < 8; j++) vv[j] = S[quad * 8 + j][f];
        *(bf16x8*)(WeTp + (size_t)e * 16384 +
                   ((size_t)(nt * 4 + qd) * 64 + lane) * 8) = vv;   // coalesced
    }
}

// ---------------------------------------------------------------------------
// Load one expert's B fragments (2 n-tiles x 4 k-steps) from packed WeTp.
// Each load: lane-consecutive 16B -> one 1KB coalesced transaction.
// ---------------------------------------------------------------------------
__device__ __forceinline__ void loadBp(
    bf16x8 (&dst)[2][4], const __bf16* __restrict__ WeTp,
    int e, int wid, int lane)
{
    const __bf16* b = WeTp + (size_t)e * 16384 + (size_t)lane * 8;
    #pragma unroll
    for (int t2 = 0; t2 < 2; t2++)
        #pragma unroll
        for (int s = 0; s < 4; s++)
            dst[t2][s] = *(const bf16x8*)(b + ((wid * 2 + t2) * 4 + s) * 512);
}

// ---------------------------------------------------------------------------
// K1: FUSED gate + expert. 64 tokens/block, 4 waves.
// Gate: scalar fp64 dots (R0-proven numerics) with Wg/Wn pre-converted to
// fp64 in LDS (cvt removal); G3 fused in-register -> single ga[] write.
// Top-3 -> comb -> dense MFMA expert loop (register-resident Af + dbuf
// coalesced B) -> bias epilogue -> coalesced store (two 32-row halves).
// Importance: LDS partials -> one global atomicAdd per expert per block;
// LAST block (ticket) computes the loss (replaces k_loss launch).
// LDS 52.3K:
//   union u: ga fp64 [64][17] (8.7K) | xsb bf16 [64][136] (17.4K)
//   union v: wgD+wnD fp64 (33.3K, dead after G2) | beS+combT (12.5K)
//            | yh f32 [32][132] (16.9K, epilogue only)
// MFMA 16x16x32 layouts (m89-verified):
//   A: lane l holds A[m=l&15][k=(l>>4)*8+j]; D: col=l&15, row=(l>>4)*4+reg
// ---------------------------------------------------------------------------
__global__ __launch_bounds__(256, 2) void k_fused(
    const float* __restrict__ x, const float* __restrict__ noise,
    const float* __restrict__ Wg, const float* __restrict__ bg,
    const float* __restrict__ Wn, const float* __restrict__ bn,
    const __bf16* __restrict__ WeTp, const float* __restrict__ be,
    float* __restrict__ out, float* __restrict__ imp_g,
    unsigned* __restrict__ ticket)
{
    __shared__ union {
        double ga[TPB][NE + 1];                                        // 8.7K
        __bf16 xsb[TPB][DD + 8];                                       // 17.4K
    } u;
    __shared__ union {
        struct { double wgD[NE][DD + 2]; double wnD[NE][DD + 2]; } w;  // 33.3K
        struct { float beS[NE][DD]; float combT[NE][TPB + 4]; } p;     // 12.5K
        float yh[32][DD + 4];                                          // 16.9K
    } v;
    __shared__ float tkw[TPB][NK];
    __shared__ int   tke[TPB][NK];
    __shared__ float impS[NE];

    const int tid  = threadIdx.x;
    const int n0   = blockIdx.x * TPB;
    const int lane = tid & 63;
    const int wid  = tid >> 6;             // wave -> cols wid*32..+31 (expert)
    const int l15  = lane & 15;
    const int quad = lane >> 4;
    const int e16  = tid & 15;             // gate-phase expert id
    const int tl   = tid >> 4;             // gate-phase token lane

    // Early-issue expert-0 B fragments: L2 latency hides under gate phase.
    bf16x8 Bf[2][2][4];
    loadBp(Bf[0], WeTp, 0, wid, lane);

    // ---- G1: stage gate weights as fp64 (cvt once); zero impS ----
    if (tid < NE) impS[tid] = 0.0f;
    for (int i = tid; i < DD * NE; i += 256) {
        int d = i >> 4, ee = i & 15;
        v.w.wgD[ee][d] = (double)Wg[i];
        v.w.wnD[ee][d] = (double)Wn[i];
    }
    __syncthreads();

    // ---- G2+G3 fused: fp64 dots (8 indep chains) + bias/noise/softplus ----
    // Identical arithmetic to R0: g0..g3 partial sums by k mod 4, then
    // (g0+g1)+(g2+g3); f32->f64 converts are exact.
    {
        const double2* wgp = (const double2*)&v.w.wgD[e16][0];
        const double2* wnp = (const double2*)&v.w.wnD[e16][0];
        const double bge = (double)bg[e16], bne = (double)bn[e16];
        for (int g = 0; g < 4; g++) {
            int t = g * 16 + tl;
            const float4* xp = (const float4*)(x + (size_t)(n0 + t) * DD);
            double g0 = 0, g1 = 0, g2 = 0, g3 = 0;
            double h0 = 0, h1 = 0, h2 = 0, h3 = 0;
            #pragma unroll 4
            for (int q = 0; q < DD / 4; q++) {
                float4 xv = xp[q];
                double2 wga = wgp[2 * q], wgb = wgp[2 * q + 1];
                double2 wna = wnp[2 * q], wnb = wnp[2 * q + 1];
                double x0 = (double)xv.x, x1 = (double)xv.y;
                double x2 = (double)xv.z, x3 = (double)xv.w;
                g0 += x0 * wga.x; g1 += x1 * wga.y;
                g2 += x2 * wgb.x; g3 += x3 * wgb.y;
                h0 += x0 * wna.x; h1 += x1 * wna.y;
                h2 += x2 * wnb.x; h3 += x3 * wnb.y;
            }
            double nz = (double)noise[(size_t)(n0 + t) * NE + e16];
            u.ga[t][e16] = ((g0 + g1) + (g2 + g3)) + bge
                         + nz * softplus_d(((h0 + h1) + (h2 + h3)) + bne);
        }
    }
    __syncthreads();

    // ---- G4: top-3 + softmax (64 threads) ----
    if (tid < TPB) {
        int t = tid;
        double vk[NK]; int ix[NK];
        unsigned taken = 0;
        for (int k = 0; k < NK; k++) {
            double best = -INFINITY; int bi = 0;
            for (int j = 0; j < NE; j++) {
                if (!((taken >> j) & 1u)) {
                    double gv = u.ga[t][j];
                    if (gv > best) { best = gv; bi = j; }  // strict >: low idx tie
                }
            }
            taken |= 1u << bi;
            vk[k] = best; ix[k] = bi;
        }
        double e1 = exp(vk[1] - vk[0]);
        double e2 = exp(vk[2] - vk[0]);
        double inv = 1.0 / (1.0 + e1 + e2);
        tke[t][0] = ix[0]; tke[t][1] = ix[1]; tke[t][2] = ix[2];
        tkw[t][0] = (float)inv;
        tkw[t][1] = (float)(e1 * inv);
        tkw[t][2] = (float)(e2 * inv);
    }
    __syncthreads();   // ga dead -> xsb; wgD/wnD dead -> v.p

    // ---- G5/X1: comb (global + LDS combT), impS, beS, xsb staging ----
    for (int g = 0; g < 4; g++) {
        int t = g * 16 + tl;
        float c = 0.f;
        if (tke[t][0] == e16) c = tkw[t][0];
        if (tke[t][1] == e16) c = tkw[t][1];
        if (tke[t][2] == e16) c = tkw[t][2];
        out[OUT_COMB + (size_t)(n0 + t) * NE + e16] = c;
        v.p.combT[e16][t] = c;
        if (c != 0.f) atomicAdd(&impS[e16], c);
    }
    for (int idx = tid; idx < NE * DD; idx += 256)      // stage be
        v.p.beS[idx >> 7][idx & 127] = be[idx];
    for (int idx = tid; idx < TPB * DD / 4; idx += 256) {  // stage x as bf16 (vec)
        int t = idx >> 5, q = idx & 31;
        float4 xv = *(const float4*)(x + (size_t)(n0 + t) * DD + q * 4);
        bf16x4 bv = { (__bf16)xv.x, (__bf16)xv.y, (__bf16)xv.z, (__bf16)xv.w };
        *(bf16x4*)&u.xsb[t][q * 4] = bv;
    }
    __syncthreads();

    // importance partials -> global (device-scope atomics)
    if (tid < NE) atomicAdd(&imp_g[tid], impS[tid]);

    // ---- X2: hoist A fragments (expert-independent, read LDS once) ----
    bf16x8 Af[4][4];
    #pragma unroll
    for (int a = 0; a < 4; a++)
        #pragma unroll
        for (int s = 0; s < 4; s++)
            Af[a][s] = *(const bf16x8*)&u.xsb[a * 16 + l15][32 * s + quad * 8];

    // ---- X3: expert loop, register-resident, dbuf coalesced B ----
    f32x4 logits[4][2];
    #pragma unroll
    for (int a = 0; a < 4; a++) {
        logits[a][0] = (f32x4){0.f, 0.f, 0.f, 0.f};
        logits[a][1] = (f32x4){0.f, 0.f, 0.f, 0.f};
    }

    #pragma unroll 2
    for (int e = 0; e < NE; e++) {
        const int cur = e & 1;
        if (e + 1 < NE) loadBp(Bf[cur ^ 1], WeTp, e + 1, wid, lane);

        f32x4 acc[4][2];
        #pragma unroll
        for (int a = 0; a < 4; a++) {
            acc[a][0] = (f32x4){0.f, 0.f, 0.f, 0.f};
            acc[a][1] = (f32x4){0.f, 0.f, 0.f, 0.f};
        }
        #pragma unroll
        for (int s = 0; s < 4; s++)        // s-outer: 8 indep chains
            #pragma unroll
            for (int a = 0; a < 4; a++) {
                acc[a][0] = __builtin_amdgcn_mfma_f32_16x16x32_bf16(
                    Af[a][s], Bf[cur][0][s], acc[a][0], 0, 0, 0);
                acc[a][1] = __builtin_amdgcn_mfma_f32_16x16x32_bf16(
                    Af[a][s], Bf[cur][1][s], acc[a][1], 0, 0, 0);
            }
        #pragma unroll
        for (int a = 0; a < 4; a++) {
            f32x4 cv = *(const f32x4*)&v.p.combT[e][a * 16 + quad * 4];
            #pragma unroll
            for (int r = 0; r < 4; r++) {
                logits[a][0][r] = fmaf(cv[r], acc[a][0][r], logits[a][0][r]);
                logits[a][1][r] = fmaf(cv[r], acc[a][1][r], logits[a][1][r]);
            }
        }
    }

    // ---- X4: bias epilogue + LDS-staged coalesced store (two halves) ----
    const int nA = wid * 32, nB = nA + 16;
    #pragma unroll 4
    for (int e = 0; e < NE; e++) {
        float bA = v.p.beS[e][nA + l15];
        float bB = v.p.beS[e][nB + l15];
        #pragma unroll
        for (int a = 0; a < 4; a++) {
            f32x4 cv = *(const f32x4*)&v.p.combT[e][a * 16 + quad * 4];
            #pragma unroll
            for (int r = 0; r < 4; r++) {
                logits[a][0][r] = fmaf(cv[r], bA, logits[a][0][r]);
                logits[a][1][r] = fmaf(cv[r], bB, logits[a][1][r]);
            }
        }
    }
    #pragma unroll
    for (int h = 0; h < 2; h++) {
        __syncthreads();                    // h=0: after v.p reads; h=1: after copy
        #pragma unroll
        for (int a2 = 0; a2 < 2; a2++) {
            const int a = h * 2 + a2;
            #pragma unroll
            for (int r = 0; r < 4; r++) {
                int row = a2 * 16 + quad * 4 + r;   // 0..31 within half
                v.yh[row][nA + l15] = logits[a][0][r];
                v.yh[row][nB + l15] = logits[a][1][r];
            }
        }
        __syncthreads();
        float4* op4 = (float4*)(out + ((size_t)n0 + h * 32) * DD);
        for (int idx = tid; idx < 32 * DD / 4; idx += 256) {
            int t = idx >> 5, q = idx & 31;
            op4[idx] = *(const float4*)&v.yh[t][q * 4];
        }
    }

    // ---- ticket: last block computes importance loss (replaces k_loss) ----
    if (tid == 0) {
        __threadfence();                       // my block's atomics visible
        unsigned prev = atomicAdd(ticket, 1u);
        if (prev == NBLK - 1) {
            __threadfence();
            double vals[NE];
            double mean = 0.0;
            for (int i = 0; i < NE; i++) {
                vals[i] = (double)atomicAdd(&imp_g[i], 0.0f);  // coherent read
                mean += vals[i];
            }
            mean /= NE;
            double var = 0.0;
            for (int i = 0; i < NE; i++) {
                double d = vals[i] - mean; var += d * d;
            }
            var /= (NE - 1);                    // ddof=1
            out[OUT_LOSS] = (float)(var / (mean * mean));
        }
    }
}

// ---------------------------------------------------------------------------
extern "C" void kernel_launch(void* const* d_in, const int* in_sizes, int n_in,
                              void* d_out, int out_size, void* d_ws, size_t ws_size,
                              hipStream_t stream)
{
    (void)in_sizes; (void)n_in; (void)out_size; (void)ws_size;
    const float* x     = (const float*)d_in[0];
    const float* noise = (const float*)d_in[1];
    const float* Wg    = (const float*)d_in[2];
    const float* bg    = (const float*)d_in[3];
    const float* Wn    = (const float*)d_in[4];
    const float* bn    = (const float*)d_in[5];
    const float* We    = (const float*)d_in[6];
    const float* be    = (const float*)d_in[7];
    float* out = (float*)d_out;

    char*     ws     = (char*)d_ws;
    float*    imp_g  = (float*)ws;               // 64 B (16 floats)
    unsigned* ticket = (unsigned*)(ws + 128);    // 4 B
    __bf16*   WeTp   = (__bf16*)(ws + 1024);     // 512 KB, 16B-aligned

    hipLaunchKernelGGL(k_prep, dim3(64), dim3(256), 0, stream,
                       We, WeTp, imp_g, ticket);
    hipLaunchKernelGGL(k_fused, dim3(NBLK), dim3(256), 0, stream,
                       x, noise, Wg, bg, Wn, bn, WeTp, be, out, imp_g, ticket);
}

// Round 4
// 156.867 us; speedup vs baseline: 2.2642x; 1.2906x over previous
//
#include <hip/hip_runtime.h>
#include <math.h>

// SparseMOELayer: N=65536 tokens, D=128, E=16 experts, top-3 routing.
// Outputs concat: logits[N*D] | importance_loss[1] | comb[N*E]
//
// R4: base = R0 (proven 93us k_fused). Single-theme change: cut gate-phase
// work in place, numerics bit-identical.
//  (a) G2 q-outer/g-inner: W row load+cvt hoisted out of the token loop
//      (-768 v_cvt_f64_f32, -192 ds_read_b128 per thread); each fp64
//      accumulator chain keeps R0's exact op order -> identical top-k.
//  (b) G3 fused into G2 epilogue in-register: na[] LDS array + 1 barrier
//      removed.
//  (c) Vectorized bf16 restage (float4->bf16x4) and final store (float4),
//      keeping R0's single-phase full yacc (no new barriers).
// NOT changed (lessons R1/R3): launch_bounds stays (256,2) (unified
// VGPR+AGPR need ~190; (256,4) spilled 1GB). W stays fp32 in LDS (fp64
// staging made G2 LDS-BW-bound). k_loss stays separate (per-block
// __threadfence for ticket merge caused L2-writeback stalls).
#define NTOK 65536
#define DD   128
#define NE   16
#define NK   3
#define TPB  64                    // tokens per block
#define NBLK (NTOK / TPB)          // 1024

#define OUT_LOSS ((size_t)NTOK * DD)
#define OUT_COMB ((size_t)NTOK * DD + 1)

typedef __bf16 bf16x8 __attribute__((ext_vector_type(8)));
typedef __bf16 bf16x4 __attribute__((ext_vector_type(4)));
typedef float  f32x4  __attribute__((ext_vector_type(4)));

__device__ __forceinline__ double softplus_d(double z) {
    return fmax(z, 0.0) + log1p(exp(-fabs(z)));
}

// ---------------------------------------------------------------------------
// K0: pack We[e][d][f] fp32 -> WeTp bf16, FRAGMENT-MAJOR:
//   WeTp[e][nt][s][lane][j]  (flat: e*16384 + (nt*4+s)*512 + lane*8 + j)
//   holds We[d = s*32 + (lane>>4)*8 + j][f = nt*16 + (lane&15)].
// Consumer loadBp then reads one bf16x8/lane at consecutive 16B -> each
// B-frag load is ONE coalesced 1KB transaction.
// 64 blocks: (expert e = blk>>2, k-step s = blk&3). Block 0 zeroes imp_g.
// ---------------------------------------------------------------------------
__global__ __launch_bounds__(256) void k_prep(
    const float* __restrict__ We, __bf16* __restrict__ WeTp,
    float* __restrict__ imp_g)
{
    __shared__ __bf16 S[32][DD + 8];
    const int tid = threadIdx.x;
    const int e  = blockIdx.x >> 2;
    const int qd = blockIdx.x & 3;             // == k-step s
    if (blockIdx.x == 0 && tid < NE) imp_g[tid] = 0.f;
    const size_t base = (size_t)e * DD * DD + (size_t)qd * 32 * DD;
    for (int i = tid; i < 32 * DD; i += 256) { // coalesced read, d-quarter
        int dd = i >> 7, f = i & 127;
        S[dd][f] = (__bf16)We[base + i];
    }
    __syncthreads();
    #pragma unroll
    for (int it = 0; it < 2; it++) {
        int lin  = it * 256 + tid;             // 0..511 vectors
        int nt   = lin >> 6;
        int lane = lin & 63;
        int quad = lane >> 4, l15 = lane & 15;
        int f = nt * 16 + l15;
        bf16x8 vv;
        #pragma unroll
        for (int j = 0; j < 8; j++) vv[j] = S[quad * 8 + j][f];
        *(bf16x8*)(WeTp + (size_t)e * 16384 +
                   ((size_t)(nt * 4 + qd) * 64 + lane) * 8) = vv;   // coalesced
    }
}

// ---------------------------------------------------------------------------
// Load one expert's B fragments (2 n-tiles x 4 k-steps) from packed WeTp.
// Each load: lane-consecutive 16B -> one 1KB coalesced transaction.
// ---------------------------------------------------------------------------
__device__ __forceinline__ void loadBp(
    bf16x8 (&dst)[2][4], const __bf16* __restrict__ WeTp,
    int e, int wid, int lane)
{
    const __bf16* b = WeTp + (size_t)e * 16384 + (size_t)lane * 8;
    #pragma unroll
    for (int t2 = 0; t2 < 2; t2++)
        #pragma unroll
        for (int s = 0; s < 4; s++)
            dst[t2][s] = *(const bf16x8*)(b + ((wid * 2 + t2) * 4 + s) * 512);
}

// ---------------------------------------------------------------------------
// K1: FUSED gate + expert. 64 tokens/block.
// Gate phases (fp64, R0-verified numerics; q-outer W-hoisted) -> top-3 ->
// comb (LDS-direct + global write) -> dense MFMA expert loop (register-
// resident structure, packed-coalesced B) -> bias epilogue -> coalesced
// store. Importance: LDS partials -> one global atomicAdd per expert per
// block (imp_g zeroed by k_prep, stream-ordered).
// LDS unions (52.3 KB total):
//   union u: ga fp64 (8.7K) | xsb bf16 (17.4K) | yacc f32 (33.8K)
//   union v: WgT+WnT (16.9K, dead after dot phase) | beS+combT (12.5K)
// MFMA 16x16x32 layouts (m89-verified):
//   A: lane l holds A[m=l&15][k=(l>>4)*8+j]; D: col=l&15, row=(l>>4)*4+reg
// ---------------------------------------------------------------------------
__global__ __launch_bounds__(256, 2) void k_fused(
    const float* __restrict__ x, const float* __restrict__ noise,
    const float* __restrict__ Wg, const float* __restrict__ bg,
    const float* __restrict__ Wn, const float* __restrict__ bn,
    const __bf16* __restrict__ WeTp, const float* __restrict__ be,
    float* __restrict__ out, float* __restrict__ imp_g)
{
    __shared__ union {
        double ga[TPB][NE + 1];                                        // 8.7K
        __bf16 xsb[TPB][DD + 8];                                       // 17.4K
        float  yacc[TPB][DD + 4];                                      // 33.8K
    } u;
    __shared__ union {
        struct { float WgT[NE][DD + 4]; float WnT[NE][DD + 4]; } w;    // 16.9K
        struct { float beS[NE][DD]; float combT[NE][TPB + 4]; } p;     // 12.5K
    } v;
    __shared__ float tkw[TPB][NK];
    __shared__ int   tke[TPB][NK];
    __shared__ float impS[NE];

    const int tid  = threadIdx.x;
    const int n0   = blockIdx.x * TPB;
    const int lane = tid & 63;
    const int wid  = tid >> 6;             // wave -> cols wid*32..+31
    const int l15  = lane & 15;
    const int quad = lane >> 4;
    const int e16  = tid & 15;             // gate-phase expert id
    const int tl   = tid >> 4;             // gate-phase token lane

    // ---- G1: stage transposed gate weights; zero impS ----
    if (tid < NE) impS[tid] = 0.0f;
    for (int i = tid; i < DD * NE; i += 256) {
        int d = i >> 4, ee = i & 15;
        v.w.WgT[ee][d] = Wg[i];
        v.w.WnT[ee][d] = Wn[i];
    }
    __syncthreads();

    // ---- G2+G3: fp64 dots, q-outer (W cvt hoisted across 4 tokens) ----
    // Per-chain fp64 op order identical to R0: chain j accumulates
    // x[4q+j]*w[4q+j] in ascending q; final (g0+g1)+(g2+g3); exact f32->f64
    // converts -> bit-identical gate values, identical top-k.
    {
        const float4* wgp = (const float4*)&v.w.WgT[e16][0];
        const float4* wnp = (const float4*)&v.w.WnT[e16][0];
        const float4* xp[4];
        #pragma unroll
        for (int g = 0; g < 4; g++)
            xp[g] = (const float4*)(x + (size_t)(n0 + g * 16 + tl) * DD);

        double Ga[4][4], Ha[4][4];
        #pragma unroll
        for (int g = 0; g < 4; g++)
            #pragma unroll
            for (int j = 0; j < 4; j++) { Ga[g][j] = 0.0; Ha[g][j] = 0.0; }

        #pragma unroll 2
        for (int q = 0; q < DD / 4; q++) {
            float4 wg = wgp[q], wn = wnp[q];
            double wg0 = (double)wg.x, wg1 = (double)wg.y;
            double wg2 = (double)wg.z, wg3 = (double)wg.w;
            double wn0 = (double)wn.x, wn1 = (double)wn.y;
            double wn2 = (double)wn.z, wn3 = (double)wn.w;
            float4 xv[4];
            #pragma unroll
            for (int g = 0; g < 4; g++) xv[g] = xp[g][q];
            #pragma unroll
            for (int g = 0; g < 4; g++) {
                double x0 = (double)xv[g].x, x1 = (double)xv[g].y;
                double x2 = (double)xv[g].z, x3 = (double)xv[g].w;
                Ga[g][0] += x0 * wg0; Ga[g][1] += x1 * wg1;
                Ga[g][2] += x2 * wg2; Ga[g][3] += x3 * wg3;
                Ha[g][0] += x0 * wn0; Ha[g][1] += x1 * wn1;
                Ha[g][2] += x2 * wn2; Ha[g][3] += x3 * wn3;
            }
        }

        const double bge = (double)bg[e16], bne = (double)bn[e16];
        #pragma unroll
        for (int g = 0; g < 4; g++) {
            int t = g * 16 + tl;
            double gsum = (Ga[g][0] + Ga[g][1]) + (Ga[g][2] + Ga[g][3]);
            double hsum = (Ha[g][0] + Ha[g][1]) + (Ha[g][2] + Ha[g][3]);
            double nz = (double)noise[(size_t)(n0 + t) * NE + e16];
            u.ga[t][e16] = gsum + bge + nz * softplus_d(hsum + bne);
        }
    }
    __syncthreads();

    // ---- G4: top-3 + softmax (64 threads) ----
    if (tid < TPB) {
        int t = tid;
        double vk[NK]; int ix[NK];
        unsigned taken = 0;
        for (int k = 0; k < NK; k++) {
            double best = -INFINITY; int bi = 0;
            for (int j = 0; j < NE; j++) {
                if (!((taken >> j) & 1u)) {
                    double gv = u.ga[t][j];
                    if (gv > best) { best = gv; bi = j; }  // strict >: low idx tie
                }
            }
            taken |= 1u << bi;
            vk[k] = best; ix[k] = bi;
        }
        double e1 = exp(vk[1] - vk[0]);
        double e2 = exp(vk[2] - vk[0]);
        double inv = 1.0 / (1.0 + e1 + e2);
        tke[t][0] = ix[0]; tke[t][1] = ix[1]; tke[t][2] = ix[2];
        tkw[t][0] = (float)inv;
        tkw[t][1] = (float)(e1 * inv);
        tkw[t][2] = (float)(e2 * inv);
    }
    __syncthreads();   // gate scratch (u.ga) dead; v.w dead -> stage new data

    // ---- G5/X1: comb (global + LDS combT), impS, beS, xsb staging ----
    for (int g = 0; g < 4; g++) {
        int t = g * 16 + tl;
        float c = 0.f;
        if (tke[t][0] == e16) c = tkw[t][0];
        if (tke[t][1] == e16) c = tkw[t][1];
        if (tke[t][2] == e16) c = tkw[t][2];
        out[OUT_COMB + (size_t)(n0 + t) * NE + e16] = c;
        v.p.combT[e16][t] = c;
        if (c != 0.f) atomicAdd(&impS[e16], c);
    }
    for (int idx = tid; idx < NE * DD; idx += 256)      // stage be
        v.p.beS[idx >> 7][idx & 127] = be[idx];
    for (int idx = tid; idx < TPB * DD / 4; idx += 256) {  // stage x as bf16 (vec)
        int t = idx >> 5, q = idx & 31;
        float4 xv = *(const float4*)(x + (size_t)(n0 + t) * DD + q * 4);
        bf16x4 bv = { (__bf16)xv.x, (__bf16)xv.y, (__bf16)xv.z, (__bf16)xv.w };
        *(bf16x4*)&u.xsb[t][q * 4] = bv;
    }
    __syncthreads();

    // importance partials -> global (device-scope atomics)
    if (tid < NE) atomicAdd(&imp_g[tid], impS[tid]);

    // ---- X2: hoist A fragments (expert-independent, read LDS once) ----
    bf16x8 Af[4][4];
    #pragma unroll
    for (int a = 0; a < 4; a++)
        #pragma unroll
        for (int s = 0; s < 4; s++)
            Af[a][s] = *(const bf16x8*)&u.xsb[a * 16 + l15][32 * s + quad * 8];
    __syncthreads();   // xsb dead -> u.yacc reusable

    // ---- X3: expert loop, register-resident, dbuf coalesced B ----
    f32x4 logits[4][2];
    #pragma unroll
    for (int a = 0; a < 4; a++) {
        logits[a][0] = (f32x4){0.f, 0.f, 0.f, 0.f};
        logits[a][1] = (f32x4){0.f, 0.f, 0.f, 0.f};
    }
    bf16x8 Bf[2][2][4];
    loadBp(Bf[0], WeTp, 0, wid, lane);

    #pragma unroll 2
    for (int e = 0; e < NE; e++) {
        const int cur = e & 1;
        if (e + 1 < NE) loadBp(Bf[cur ^ 1], WeTp, e + 1, wid, lane);

        f32x4 acc[4][2];
        #pragma unroll
        for (int a = 0; a < 4; a++) {
            acc[a][0] = (f32x4){0.f, 0.f, 0.f, 0.f};
            acc[a][1] = (f32x4){0.f, 0.f, 0.f, 0.f};
        }
        #pragma unroll
        for (int s = 0; s < 4; s++)        // s-outer: 8 indep chains
            #pragma unroll
            for (int a = 0; a < 4; a++) {
                acc[a][0] = __builtin_amdgcn_mfma_f32_16x16x32_bf16(
                    Af[a][s], Bf[cur][0][s], acc[a][0], 0, 0, 0);
                acc[a][1] = __builtin_amdgcn_mfma_f32_16x16x32_bf16(
                    Af[a][s], Bf[cur][1][s], acc[a][1], 0, 0, 0);
            }
        #pragma unroll
        for (int a = 0; a < 4; a++) {
            f32x4 cv = *(const f32x4*)&v.p.combT[e][a * 16 + quad * 4];
            #pragma unroll
            for (int r = 0; r < 4; r++) {
                logits[a][0][r] = fmaf(cv[r], acc[a][0][r], logits[a][0][r]);
                logits[a][1][r] = fmaf(cv[r], acc[a][1][r], logits[a][1][r]);
            }
        }
    }

    // ---- X4: bias epilogue + LDS-staged coalesced store ----
    const int nA = wid * 32, nB = nA + 16;
    #pragma unroll 4
    for (int e = 0; e < NE; e++) {
        float bA = v.p.beS[e][nA + l15];
        float bB = v.p.beS[e][nB + l15];
        #pragma unroll
        for (int a = 0; a < 4; a++) {
            f32x4 cv = *(const f32x4*)&v.p.combT[e][a * 16 + quad * 4];
            #pragma unroll
            for (int r = 0; r < 4; r++) {
                logits[a][0][r] = fmaf(cv[r], bA, logits[a][0][r]);
                logits[a][1][r] = fmaf(cv[r], bB, logits[a][1][r]);
            }
        }
    }
    #pragma unroll
    for (int a = 0; a < 4; a++) {
        #pragma unroll
        for (int r = 0; r < 4; r++) {
            int row = a * 16 + quad * 4 + r;
            u.yacc[row][nA + l15] = logits[a][0][r];
            u.yacc[row][nB + l15] = logits[a][1][r];
        }
    }
    __syncthreads();
    float4* op4 = (float4*)(out + (size_t)n0 * DD);
    for (int idx = tid; idx < TPB * DD / 4; idx += 256) {
        int t = idx >> 5, q = idx & 31;
        op4[idx] = *(const float4*)&u.yacc[t][q * 4];
    }
}

// ---------------------------------------------------------------------------
// K2: loss from 16 globally-accumulated importances (atomic sums from k_fused).
// ---------------------------------------------------------------------------
__global__ __launch_bounds__(64) void k_loss(
    const float* __restrict__ imp_g, float* __restrict__ out)
{
    if (threadIdx.x == 0) {
        double mean = 0.0;
        for (int i = 0; i < NE; i++) mean += (double)imp_g[i];
        mean /= NE;
        double var = 0.0;
        for (int i = 0; i < NE; i++) {
            double d = (double)imp_g[i] - mean; var += d * d;
        }
        var /= (NE - 1);                    // ddof=1
        out[OUT_LOSS] = (float)(var / (mean * mean));
    }
}

// ---------------------------------------------------------------------------
extern "C" void kernel_launch(void* const* d_in, const int* in_sizes, int n_in,
                              void* d_out, int out_size, void* d_ws, size_t ws_size,
                              hipStream_t stream)
{
    (void)in_sizes; (void)n_in; (void)out_size; (void)ws_size;
    const float* x     = (const float*)d_in[0];
    const float* noise = (const float*)d_in[1];
    const float* Wg    = (const float*)d_in[2];
    const float* bg    = (const float*)d_in[3];
    const float* Wn    = (const float*)d_in[4];
    const float* bn    = (const float*)d_in[5];
    const float* We    = (const float*)d_in[6];
    const float* be    = (const float*)d_in[7];
    float* out = (float*)d_out;

    char*   ws    = (char*)d_ws;
    float*  imp_g = (float*)ws;                  // 64 B (16 floats)
    __bf16* WeTp  = (__bf16*)(ws + 1024);        // 512 KB, 16B-aligned

    hipLaunchKernelGGL(k_prep, dim3(64), dim3(256), 0, stream,
                       We, WeTp, imp_g);
    hipLaunchKernelGGL(k_fused, dim3(NBLK), dim3(256), 0, stream,
                       x, noise, Wg, bg, Wn, bn, WeTp, be, out, imp_g);
    hipLaunchKernelGGL(k_loss, dim3(1), dim3(64), 0, stream, imp_g, out);
}